// Round 6
// baseline (167.929 us; speedup 1.0000x reference)
//
#include <hip/hip_runtime.h>
#include <math.h>

// CIRNet: T=1048576 rows x 18 feats. Outputs concat: r_predicts[N], regs[N], dts[N], N=T-1.
// SINGLE kernel: each thread owns 4 consecutive steps; reads its 288B trace slice,
// computes per-step coeffs in registers, writes regs/dts, runs the Newton-linearized
// 4-step forward from an ODE closed-form seed -> block affine scan -> device-wide
// ticket barrier (init-free __device__ global, monotone across graph replays) ->
// global scan of 256 block aggregates -> replay 4 steps -> float4 store.
// Per-step map: r' = a*r + b + c*sqrt(|r|), a = 1-k*d, b = k*th*d, c = sig*eps*sqrt(d).
// Pad step (n=NSTEPS) uses (d,c)=(0,0) -> exact identity map.
#define NSTEPS  1048575
#define FEAT    18
#define NT      1024
#define NB      256               // <= 256 CUs -> all blocks co-resident
#define CHUNKS  (NT * NB)         // 262144 threads x 4 steps = 1048576 >= NSTEPS

__device__ unsigned int g_ticket = 0;          // monotone ticket barrier (never reset)
__device__ float gAb[NB], gBb[NB];             // block affine aggregates

// one step + derivative-product update
#define GSTEP(dd, cc) { \
    float a   = fmaf(-k, (dd), 1.f); \
    float b   = kth * (dd); \
    float ar  = fabsf(r); \
    float sq  = sqrtf(ar); \
    float inv = (ar > 1e-30f) ? rsqrtf(ar) : 0.f; \
    float g   = fmaf(0.5f * (cc), copysignf(inv, r), a); \
    r = fmaf((cc), sq, fmaf(a, r, b)); \
    P *= g; }

#define FSTEP(dd, cc) { \
    float a = fmaf(-k, (dd), 1.f); \
    float b = kth * (dd); \
    rr = fmaf((cc), sqrtf(fabsf(rr)), fmaf(a, rr, b)); }

__device__ __forceinline__ void wave_scan_affine(float& A, float& B, int lane) {
#pragma unroll
    for (int d = 1; d < 64; d <<= 1) {
        float pA = __shfl_up(A, d, 64);
        float pB = __shfl_up(B, d, 64);
        if (lane >= d) { B = fmaf(A, pB, B); A *= pA; }
    }
}

__global__ void __launch_bounds__(NT) cir_one(
    const float* __restrict__ trace,
    const float* __restrict__ sW, const float* __restrict__ sb,
    const float* __restrict__ eW, const float* __restrict__ kp,
    const float* __restrict__ thp,
    float* __restrict__ out)
{
    __shared__ float wAs[16], wBs[16];
    __shared__ float sgA[NB], sgB[NB];
    const int tid = threadIdx.x, lane = tid & 63, wid = tid >> 6, bid = blockIdx.x;
    const int c = bid * NT + tid;
    const bool lastc = (c == CHUNKS - 1);

    const float k = kp[0], th = thp[0], kth = k * th;
    const float sbv = sb[0];
    float sWv[8], eWv[8];
#pragma unroll
    for (int j = 0; j < 8; ++j) { sWv[j] = sW[j]; eWv[j] = eW[j]; }

    // ---- load this thread's 4 rows (72 floats, 16B-aligned slice) ----
    float L[72];
    const float4* tp = (const float4*)(trace + 72l * c);
#pragma unroll
    for (int i = 0; i < 18; ++i) ((float4*)L)[i] = tp[i];
    float t4 = lastc ? L[54] : trace[72l * (c + 1)];   // t_{4c+4} (dummy for last)

    // ---- per-step coefficients + regs/dts writes ----
    float dv[4], cv[4];
#pragma unroll
    for (int i = 0; i < 4; ++i) {
        int base = 18 * i;
        float tn1 = (i < 3) ? L[base + 18] : t4;
        float d = tn1 - L[base];
        float sig = sbv;
#pragma unroll
        for (int j = 0; j < 8; ++j) sig = fmaf(L[base + 2 + j], sWv[j], sig);
        float ep = 0.f;
#pragma unroll
        for (int j = 0; j < 8; ++j) ep = fmaf(L[base + 10 + j], eWv[j], ep);
        bool valid = (i < 3) || !lastc;
        dv[i] = valid ? d : 0.f;
        cv[i] = valid ? sig * ep * sqrtf(fabsf(d)) : 0.f;
        if (valid) {
            int n = 4 * c + i;
            out[NSTEPS + n]     = fmaf(-sig, sig, 2.f * k * th);  // regs
            out[2 * NSTEPS + n] = d;                              // dts
        }
    }

    // ---- ODE closed-form seed + linearized 4-step forward ----
    const float r0 = trace[1];
    const float s = th + (r0 - th) * __expf(-k * (L[0] - trace[0]));
    float r = s, P = 1.f;
    GSTEP(dv[0], cv[0])
    GSTEP(dv[1], cv[1])
    GSTEP(dv[2], cv[2])
    GSTEP(dv[3], cv[3])
    float A = P, B = fmaf(-P, s, r);

    // ---- block-level inclusive scan over 1024 thread maps ----
    float iA = A, iB = B;
    wave_scan_affine(iA, iB, lane);
    if (lane == 63) { wAs[wid] = iA; wBs[wid] = iB; }
    __syncthreads();
    if (wid == 0) {
        float aA = (lane < 16) ? wAs[lane] : 1.f;
        float aB = (lane < 16) ? wBs[lane] : 0.f;
        wave_scan_affine(aA, aB, lane);
        if (lane < 16) { wAs[lane] = aA; wBs[lane] = aB; }
    }
    __syncthreads();
    float weA = 1.f, weB = 0.f;
    if (wid > 0) { weA = wAs[wid - 1]; weB = wBs[wid - 1]; }
    float eA = __shfl_up(iA, 1, 64), eB = __shfl_up(iB, 1, 64);
    if (lane == 0) { eA = 1.f; eB = 0.f; }
    float Ate = eA * weA;                 // thread-exclusive prefix within block
    float Bte = fmaf(eA, weB, eB);

    // ---- publish block aggregate + init-free device-wide ticket barrier ----
    if (tid == 0) {
        __hip_atomic_store(&gAb[bid], wAs[15], __ATOMIC_RELAXED, __HIP_MEMORY_SCOPE_AGENT);
        __hip_atomic_store(&gBb[bid], wBs[15], __ATOMIC_RELAXED, __HIP_MEMORY_SCOPE_AGENT);
        unsigned int tk = __hip_atomic_fetch_add(&g_ticket, 1u, __ATOMIC_ACQ_REL,
                                                 __HIP_MEMORY_SCOPE_AGENT);
        unsigned int target = (tk / NB + 1u) * NB;   // end of this launch's generation
        while (__hip_atomic_load(&g_ticket, __ATOMIC_ACQUIRE, __HIP_MEMORY_SCOPE_AGENT) < target)
            __builtin_amdgcn_s_sleep(1);
    }
    __syncthreads();

    // ---- every block redundantly scans the 256 block aggregates ----
    if (tid < NB) {
        sgA[tid] = __hip_atomic_load(&gAb[tid], __ATOMIC_RELAXED, __HIP_MEMORY_SCOPE_AGENT);
        sgB[tid] = __hip_atomic_load(&gBb[tid], __ATOMIC_RELAXED, __HIP_MEMORY_SCOPE_AGENT);
    }
    __syncthreads();
    for (int d = 1; d < NB; d <<= 1) {
        float pA = 1.f, pB = 0.f;
        bool act = (tid < NB) && (tid >= d);
        if (act) { pA = sgA[tid - d]; pB = sgB[tid - d]; }
        __syncthreads();
        if (act) { sgB[tid] = fmaf(sgA[tid], pB, sgB[tid]); sgA[tid] *= pA; }
        __syncthreads();
    }
    float beA = 1.f, beB = 0.f;
    if (bid > 0) { beA = sgA[bid - 1]; beB = sgB[bid - 1]; }

    // ---- corrected start, replay 4 steps, store r_predicts ----
    float FA = Ate * beA;
    float FB = fmaf(Ate, beB, Bte);
    float rr = fmaf(FA, r0, FB);
    float4 ov;
    FSTEP(dv[0], cv[0]) ov.x = rr;
    FSTEP(dv[1], cv[1]) ov.y = rr;
    FSTEP(dv[2], cv[2]) ov.z = rr;
    FSTEP(dv[3], cv[3]) ov.w = rr;
    int nb = 4 * c;
    if (!lastc) {
        *(float4*)(out + nb) = ov;
    } else {                       // step NSTEPS is pad
        out[nb + 0] = ov.x;
        out[nb + 1] = ov.y;
        out[nb + 2] = ov.z;
    }
}

extern "C" void kernel_launch(void* const* d_in, const int* in_sizes, int n_in,
                              void* d_out, int out_size, void* d_ws, size_t ws_size,
                              hipStream_t stream)
{
    const float* trace = (const float*)d_in[0];
    const float* sW    = (const float*)d_in[1];
    const float* sb    = (const float*)d_in[2];
    const float* eW    = (const float*)d_in[3];
    const float* kp    = (const float*)d_in[4];
    const float* thp   = (const float*)d_in[5];
    float* out = (float*)d_out;

    cir_one<<<NB, NT, 0, stream>>>(trace, sW, sb, eW, kp, thp, out);
}